// Round 6
// baseline (180.240 us; speedup 1.0000x reference)
//
#include <hip/hip_runtime.h>
#include <hip/hip_bf16.h>

#define N_NODES 50000
#define N_EDGES 800000
#define D_IN 96
#define D_OUT 128
#define CAP 64              // deg ~ Poisson(16); P(deg>=64) ~ e^-41 -> no drops

// XCD-sliced fill: 8 slices x 6250 nodes; block group g = blockIdx&7 lands on
// XCD g (round-robin heuristic) and bins only dst in slice g -> bucket/cursor
// lines written from ONE XCD, merging in its L2 instead of churning HBM.
#define SLICES 8
#define NODES_PER_SLICE 6250
#define GROUP_BLOCKS 256
#define FILL_BLOCKS (SLICES * GROUP_BLOCKS)         // 2048
#define EDGES_PER_BLOCK 3125                        // 3125*256 = 800000 exactly

#define CONV_THREADS (N_NODES * 12)                 // 600000
#define CONV_BLOCKS ((CONV_THREADS + 255) / 256)    // 2344

// fused agg+gemm: 64 nodes per block (4 waves x 16-node MFMA tiles)
#define NPB 64
#define AG_BLOCKS ((N_NODES + NPB - 1) / NPB)       // 782
#define AH_PITCH 104        // u16/row (96 + 8 pad): fragment reads 2-way max

typedef unsigned short u16;
typedef __attribute__((ext_vector_type(8))) short short8;   // 8 x bf16 (4 VGPRs)
typedef __attribute__((ext_vector_type(4))) float f32x4;

__device__ __forceinline__ u16 f2bf(float f) {
    unsigned u = __float_as_uint(f);
    unsigned r = (u + 0x7FFFu + ((u >> 16) & 1u)) >> 16;   // RNE
    return (u16)r;
}
__device__ __forceinline__ float bf2f(u16 h) {
    return __uint_as_float(((unsigned)h) << 16);
}

// ---------------------------------------------------------------------------
// K1: heterogeneous XCD-sliced fill + x->bf16 convert (unchanged from R5).
// ---------------------------------------------------------------------------
__global__ __launch_bounds__(256) void sage_fill_conv(
    const int* __restrict__ src,
    const int* __restrict__ dst,
    const float* __restrict__ x,
    int* __restrict__ cursor,
    u16* __restrict__ bucket,
    u16* __restrict__ xh)
{
    const int b = blockIdx.x;
    if (b < FILL_BLOCKS) {
        const int slice = b & 7;
        const int gb = b >> 3;
        const int lo = slice * NODES_PER_SLICE;
        const int hi = lo + NODES_PER_SLICE;
        const int e0 = gb * EDGES_PER_BLOCK;
        int e1 = e0 + EDGES_PER_BLOCK;
        if (e1 > N_EDGES) e1 = N_EDGES;
        for (int e = e0 + (int)threadIdx.x; e < e1; e += 256) {
            int d = dst[e];
            int s = src[e];
            if (d >= lo && d < hi) {
                int pos = atomicAdd(&cursor[d], 1);
                if (pos < CAP) bucket[(size_t)d * CAP + pos] = (u16)s;
            }
        }
    } else {
        unsigned t = (unsigned)(b - FILL_BLOCKS) * 256u + threadIdx.x;
        if (t >= (unsigned)CONV_THREADS) return;
        unsigned n = t / 12u;
        unsigned c8 = t - n * 12u;
        const float* p = x + (size_t)n * D_IN + c8 * 8u;
        short8 v;
#pragma unroll
        for (int i = 0; i < 8; i++) v[i] = (short)f2bf(p[i]);
        *(short8*)(xh + (size_t)n * D_IN + c8 * 8u) = v;
    }
}

// ---------------------------------------------------------------------------
// K2 (fused): mean-aggregate 64 nodes into LDS, then MFMA GEMM + bias + ReLU.
// Phase A: 768 tasks (node m, chunk c8), 3 per thread, 4 gathers in flight;
//          result written bf16 into Ah[m][*] (A-fragment row-major layout).
// W fragments staged into Ws before the same single barrier.
// Phase B: per wave, 16-node tile; A-frags from Ah (LDS) kc 0..2 and xh
//          (global) kc 3..5; 48 MFMAs; epilogue col=lane&15, row=quad*4+r.
// LDS 62.5 KB -> 2 blocks/CU (8 waves/CU).
// ---------------------------------------------------------------------------
__global__ __launch_bounds__(256) void sage_agg_gemm(
    const u16* __restrict__ xh,
    const int* __restrict__ cursor,
    const u16* __restrict__ bucket,
    const float* __restrict__ Wl,
    const float* __restrict__ bl,
    const float* __restrict__ Wr,
    float* __restrict__ out)
{
    __shared__ u16 Ws[8 * 6 * 64 * 8];      // 49152 B
    __shared__ u16 Ah[NPB * AH_PITCH];      // 13312 B

    const int tid = threadIdx.x;
    const int n0 = blockIdx.x * NPB;

    // ---- stage W (fp32 -> bf16 fragments): 128 j x 24 chunks ----
    for (int idx = tid; idx < 128 * 24; idx += 256) {
        int j = idx / 24;
        int c8 = idx - j * 24;
        int kc = c8 >> 2;
        int quad = c8 & 3;
        const float* wsrc = (c8 < 12) ? (Wl + (size_t)j * D_IN + c8 * 8)
                                      : (Wr + (size_t)j * D_IN + (c8 - 12) * 8);
        int jt = j >> 4;
        int col = j & 15;
        u16* dstp = Ws + (((jt * 6 + kc) * 64) + col + 16 * quad) * 8;
#pragma unroll
        for (int i = 0; i < 8; i++) dstp[i] = f2bf(wsrc[i]);
    }

    // ---- phase A: aggregate the block's 64 nodes into Ah ----
#pragma unroll
    for (int rep = 0; rep < 3; rep++) {
        int task = rep * 256 + tid;          // 0..767
        int m = task / 12;
        int c8 = task - m * 12;
        int n = n0 + m;

        float acc[8];
#pragma unroll
        for (int i = 0; i < 8; i++) acc[i] = 0.0f;
        float invd = 0.0f;

        if (n < N_NODES) {
            int deg = cursor[n];
            int degc = deg < CAP ? deg : CAP;
            const u16* brow = bucket + (size_t)n * CAP;
            int e = 0;
            for (; e + 4 <= degc; e += 4) {
                unsigned s0 = brow[e + 0];
                unsigned s1 = brow[e + 1];
                unsigned s2 = brow[e + 2];
                unsigned s3 = brow[e + 3];
                short8 v0 = *(const short8*)(xh + s0 * (unsigned)D_IN + c8 * 8u);
                short8 v1 = *(const short8*)(xh + s1 * (unsigned)D_IN + c8 * 8u);
                short8 v2 = *(const short8*)(xh + s2 * (unsigned)D_IN + c8 * 8u);
                short8 v3 = *(const short8*)(xh + s3 * (unsigned)D_IN + c8 * 8u);
#pragma unroll
                for (int i = 0; i < 8; i++) {
                    acc[i] += bf2f((u16)v0[i]) + bf2f((u16)v1[i])
                            + bf2f((u16)v2[i]) + bf2f((u16)v3[i]);
                }
            }
            for (; e < degc; e++) {
                unsigned s = brow[e];
                short8 v = *(const short8*)(xh + s * (unsigned)D_IN + c8 * 8u);
#pragma unroll
                for (int i = 0; i < 8; i++) acc[i] += bf2f((u16)v[i]);
            }
            invd = 1.0f / fmaxf((float)deg, 1.0f);
        }

        short8 o;
#pragma unroll
        for (int i = 0; i < 8; i++) o[i] = (short)f2bf(acc[i] * invd);
        *(short8*)(Ah + m * AH_PITCH + c8 * 8) = o;
    }
    __syncthreads();

    // ---- phase B: 16-node MFMA tile per wave ----
    const int wave = tid >> 6;
    const int lane = tid & 63;
    const int m16 = lane & 15;
    const int quad = lane >> 4;
    const int tilebase = n0 + wave * 16;
    if (tilebase >= N_NODES) return;         // single barrier already passed

    int nn = tilebase + m16;
    nn = nn < N_NODES ? nn : N_NODES - 1;    // clamp A-row source (out guarded)

    const u16* arow = Ah + (wave * 16 + m16) * AH_PITCH + quad * 8;
    const u16* xrow = xh + (size_t)nn * D_IN + quad * 8;
    short8 a[6];
#pragma unroll
    for (int kc = 0; kc < 3; kc++) a[kc]     = *(const short8*)(arow + kc * 32);
#pragma unroll
    for (int kc = 0; kc < 3; kc++) a[3 + kc] = *(const short8*)(xrow + kc * 32);

#pragma unroll
    for (int jt = 0; jt < 8; jt++) {
        f32x4 acc = {0.0f, 0.0f, 0.0f, 0.0f};
#pragma unroll
        for (int kc = 0; kc < 6; kc++) {
            short8 bfrag = *(const short8*)(Ws + ((jt * 6 + kc) * 64 + lane) * 8);
            acc = __builtin_amdgcn_mfma_f32_16x16x32_bf16(a[kc], bfrag, acc, 0, 0, 0);
        }
        const int j = jt * 16 + m16;         // col = lane&15
        const float bj = bl[j];
#pragma unroll
        for (int r = 0; r < 4; r++) {
            int row = quad * 4 + r;
            int n = tilebase + row;
            if (n < N_NODES)
                out[(size_t)n * D_OUT + j] = fmaxf(acc[r] + bj, 0.0f);
        }
    }
}

extern "C" void kernel_launch(void* const* d_in, const int* in_sizes, int n_in,
                              void* d_out, int out_size, void* d_ws, size_t ws_size,
                              hipStream_t stream) {
    const float* x   = (const float*)d_in[0];
    const int* eidx  = (const int*)d_in[1];
    const float* Wl  = (const float*)d_in[2];
    const float* bl  = (const float*)d_in[3];
    const float* Wr  = (const float*)d_in[4];
    float* out = (float*)d_out;

    const int* src = eidx;                // edge_index[0]
    const int* dst = eidx + N_EDGES;      // edge_index[1]

    // ws: cursor 200192 B | bucket u16 6.4 MB | xh bf16 9.6 MB  (16.2 MB)
    char* ws = (char*)d_ws;
    int* cursor = (int*)ws;
    u16* bucket = (u16*)(ws + 200192);
    u16* xh     = (u16*)(ws + 200192 + 6400000);

    hipMemsetAsync(cursor, 0, N_NODES * sizeof(int), stream);

    {
        dim3 grid(FILL_BLOCKS + CONV_BLOCKS);   // 2048 + 2344
        sage_fill_conv<<<grid, 256, 0, stream>>>(src, dst, x, cursor, bucket, xh);
    }
    {
        dim3 grid(AG_BLOCKS);                   // 782
        sage_agg_gemm<<<grid, 256, 0, stream>>>(xh, cursor, bucket, Wl, bl, Wr, out);
    }
}

// Round 7
// 155.247 us; speedup vs baseline: 1.1610x; 1.1610x over previous
//
#include <hip/hip_runtime.h>
#include <hip/hip_bf16.h>

#define N_NODES 50000
#define N_EDGES 800000
#define D_IN 96
#define D_OUT 128
#define CAP 64              // deg ~ Poisson(16); P(deg>=64) ~ e^-41 -> no drops

// XCD-sliced fill: 8 slices x 6250 nodes; block group g = blockIdx&7 lands on
// XCD g (round-robin heuristic) and bins only dst in slice g -> bucket/cursor
// lines written from ONE XCD, merging in its L2 instead of churning HBM.
#define SLICES 8
#define NODES_PER_SLICE 6250
#define GROUP_BLOCKS 256
#define FILL_BLOCKS (SLICES * GROUP_BLOCKS)         // 2048
#define EDGES_PER_BLOCK 3125                        // 3125*256 = 800000 exactly

#define CONV_THREADS (N_NODES * 12)                 // 600000
#define CONV_BLOCKS ((CONV_THREADS + 255) / 256)    // 2344
#define WCONV_BLOCKS 12                             // 128*24 = 3072 = 12*256 tasks

// fused agg+gemm: 64 nodes per block (4 waves x 16-node MFMA tiles)
#define NPB 64
#define AG_BLOCKS ((N_NODES + NPB - 1) / NPB)       // 782
#define AH_PITCH 104        // u16/row (96 + 8 pad); 208 B = 13*16 B (b128-aligned)

typedef unsigned short u16;
typedef __attribute__((ext_vector_type(8))) short short8;   // 8 x bf16 (4 VGPRs)
typedef __attribute__((ext_vector_type(4))) float f32x4;

__device__ __forceinline__ u16 f2bf(float f) {
    unsigned u = __float_as_uint(f);
    unsigned r = (u + 0x7FFFu + ((u >> 16) & 1u)) >> 16;   // RNE
    return (u16)r;
}
__device__ __forceinline__ float bf2f(u16 h) {
    return __uint_as_float(((unsigned)h) << 16);
}

// ---------------------------------------------------------------------------
// K1: heterogeneous grid.
//   [0, FILL_BLOCKS): XCD-sliced edge binning (R5, unchanged).
//   [FILL_BLOCKS, +CONV_BLOCKS): xh = bf16(x) row-major.
//   [.., +WCONV_BLOCKS): Wfrag = bf16 B-fragment-layout [Wl|Wr] in global ws.
// fill is store-transaction bound with idle pipes; conv/wconv ride free.
// ---------------------------------------------------------------------------
__global__ __launch_bounds__(256) void sage_fill_conv(
    const int* __restrict__ src,
    const int* __restrict__ dst,
    const float* __restrict__ x,
    const float* __restrict__ Wl,
    const float* __restrict__ Wr,
    int* __restrict__ cursor,
    u16* __restrict__ bucket,
    u16* __restrict__ xh,
    u16* __restrict__ Wfrag)
{
    const int b = blockIdx.x;
    if (b < FILL_BLOCKS) {
        const int slice = b & 7;
        const int gb = b >> 3;
        const int lo = slice * NODES_PER_SLICE;
        const int hi = lo + NODES_PER_SLICE;
        const int e0 = gb * EDGES_PER_BLOCK;
        int e1 = e0 + EDGES_PER_BLOCK;
        if (e1 > N_EDGES) e1 = N_EDGES;
        for (int e = e0 + (int)threadIdx.x; e < e1; e += 256) {
            int d = dst[e];
            int s = src[e];
            if (d >= lo && d < hi) {
                int pos = atomicAdd(&cursor[d], 1);
                if (pos < CAP) bucket[(size_t)d * CAP + pos] = (u16)s;
            }
        }
    } else if (b < FILL_BLOCKS + CONV_BLOCKS) {
        unsigned t = (unsigned)(b - FILL_BLOCKS) * 256u + threadIdx.x;
        if (t >= (unsigned)CONV_THREADS) return;
        unsigned n = t / 12u;
        unsigned c8 = t - n * 12u;
        const float* p = x + (size_t)n * D_IN + c8 * 8u;
        short8 v;
#pragma unroll
        for (int i = 0; i < 8; i++) v[i] = (short)f2bf(p[i]);
        *(short8*)(xh + (size_t)n * D_IN + c8 * 8u) = v;
    } else {
        // W -> bf16 fragments: 128 j x 24 chunks (12 Wl + 12 Wr)
        int idx = (b - FILL_BLOCKS - CONV_BLOCKS) * 256 + (int)threadIdx.x; // <3072
        int j = idx / 24;
        int c8 = idx - j * 24;
        int kc = c8 >> 2;
        int quad = c8 & 3;
        const float* wsrc = (c8 < 12) ? (Wl + (size_t)j * D_IN + c8 * 8)
                                      : (Wr + (size_t)j * D_IN + (c8 - 12) * 8);
        int jt = j >> 4;
        int col = j & 15;
        short8 v;
#pragma unroll
        for (int i = 0; i < 8; i++) v[i] = (short)f2bf(wsrc[i]);
        *(short8*)(Wfrag + (((jt * 6 + kc) * 64) + col + 16 * quad) * 8) = v;
    }
}

// ---------------------------------------------------------------------------
// K2 (fused, high-occupancy): aggregate 64 nodes into LDS Ah, then MFMA.
// LDS = Ah only (13.3 KB) -> LDS allows 12 blocks/CU; VGPR-limited ~20
// waves/CU (vs R6's 8: Ws evicted to global Wfrag).
// Phase A: 768 tasks (node m, chunk c8), 3/thread; bucket indices loaded
//          8-at-a-time (b128), 8 row-gathers in flight.
// Phase B: per-wave 16-node tile; A-frags: Ah (kc 0..2) + xh global (3..5);
//          B-frags: coalesced b128 loads from Wfrag (L2-broadcast).
// Epilogue: C/D map col=lane&15, row=quad*4+r (m89/m91-verified).
// ---------------------------------------------------------------------------
__global__ __launch_bounds__(256) void sage_agg_gemm(
    const u16* __restrict__ xh,
    const int* __restrict__ cursor,
    const u16* __restrict__ bucket,
    const u16* __restrict__ Wfrag,
    const float* __restrict__ bl,
    float* __restrict__ out)
{
    __shared__ u16 Ah[NPB * AH_PITCH];      // 13312 B

    const int tid = threadIdx.x;
    const int n0 = blockIdx.x * NPB;

    // ---- phase A: aggregate the block's 64 nodes into Ah ----
#pragma unroll
    for (int rep = 0; rep < 3; rep++) {
        int task = rep * 256 + tid;          // 0..767
        int m = task / 12;
        int c8 = task - m * 12;
        int n = n0 + m;

        float acc[8];
#pragma unroll
        for (int i = 0; i < 8; i++) acc[i] = 0.0f;
        float invd = 0.0f;

        if (n < N_NODES) {
            int deg = cursor[n];
            int degc = deg < CAP ? deg : CAP;
            const u16* brow = bucket + (size_t)n * CAP;
            int e = 0;
            for (; e + 8 <= degc; e += 8) {
                short8 id = *(const short8*)(brow + e);   // 8 indices, one b128
                short8 v[8];
#pragma unroll
                for (int q = 0; q < 8; q++) {
                    unsigned s = (u16)id[q];
                    v[q] = *(const short8*)(xh + s * (unsigned)D_IN + c8 * 8u);
                }
#pragma unroll
                for (int q = 0; q < 8; q++)
#pragma unroll
                    for (int i = 0; i < 8; i++) acc[i] += bf2f((u16)v[q][i]);
            }
            if (e + 4 <= degc) {
                unsigned s0 = brow[e + 0];
                unsigned s1 = brow[e + 1];
                unsigned s2 = brow[e + 2];
                unsigned s3 = brow[e + 3];
                short8 v0 = *(const short8*)(xh + s0 * (unsigned)D_IN + c8 * 8u);
                short8 v1 = *(const short8*)(xh + s1 * (unsigned)D_IN + c8 * 8u);
                short8 v2 = *(const short8*)(xh + s2 * (unsigned)D_IN + c8 * 8u);
                short8 v3 = *(const short8*)(xh + s3 * (unsigned)D_IN + c8 * 8u);
#pragma unroll
                for (int i = 0; i < 8; i++)
                    acc[i] += bf2f((u16)v0[i]) + bf2f((u16)v1[i])
                            + bf2f((u16)v2[i]) + bf2f((u16)v3[i]);
                e += 4;
            }
            for (; e < degc; e++) {
                unsigned s = brow[e];
                short8 v = *(const short8*)(xh + s * (unsigned)D_IN + c8 * 8u);
#pragma unroll
                for (int i = 0; i < 8; i++) acc[i] += bf2f((u16)v[i]);
            }
            invd = 1.0f / fmaxf((float)deg, 1.0f);
        }

        short8 o;
#pragma unroll
        for (int i = 0; i < 8; i++) o[i] = (short)f2bf(acc[i] * invd);
        *(short8*)(Ah + m * AH_PITCH + c8 * 8) = o;
    }
    __syncthreads();

    // ---- phase B: 16-node MFMA tile per wave ----
    const int wave = tid >> 6;
    const int lane = tid & 63;
    const int m16 = lane & 15;
    const int quad = lane >> 4;
    const int tilebase = n0 + wave * 16;
    if (tilebase >= N_NODES) return;         // single barrier already passed

    int nn = tilebase + m16;
    nn = nn < N_NODES ? nn : N_NODES - 1;    // clamp A-row source (store guarded)

    const u16* arow = Ah + (wave * 16 + m16) * AH_PITCH + quad * 8;
    const u16* xrow = xh + (size_t)nn * D_IN + quad * 8;
    short8 a[6];
#pragma unroll
    for (int kc = 0; kc < 3; kc++) a[kc]     = *(const short8*)(arow + kc * 32);
#pragma unroll
    for (int kc = 0; kc < 3; kc++) a[3 + kc] = *(const short8*)(xrow + kc * 32);

#pragma unroll
    for (int jt = 0; jt < 8; jt++) {
        f32x4 acc = {0.0f, 0.0f, 0.0f, 0.0f};
#pragma unroll
        for (int kc = 0; kc < 6; kc++) {
            short8 bfrag = *(const short8*)(Wfrag + ((jt * 6 + kc) * 64 + lane) * 8);
            acc = __builtin_amdgcn_mfma_f32_16x16x32_bf16(a[kc], bfrag, acc, 0, 0, 0);
        }
        const int j = jt * 16 + m16;         // col = lane&15
        const float bj = bl[j];
#pragma unroll
        for (int r = 0; r < 4; r++) {
            int row = quad * 4 + r;
            int n = tilebase + row;
            if (n < N_NODES)
                out[(size_t)n * D_OUT + j] = fmaxf(acc[r] + bj, 0.0f);
        }
    }
}

extern "C" void kernel_launch(void* const* d_in, const int* in_sizes, int n_in,
                              void* d_out, int out_size, void* d_ws, size_t ws_size,
                              hipStream_t stream) {
    const float* x   = (const float*)d_in[0];
    const int* eidx  = (const int*)d_in[1];
    const float* Wl  = (const float*)d_in[2];
    const float* bl  = (const float*)d_in[3];
    const float* Wr  = (const float*)d_in[4];
    float* out = (float*)d_out;

    const int* src = eidx;                // edge_index[0]
    const int* dst = eidx + N_EDGES;      // edge_index[1]

    // ws: cursor 200192 B | bucket u16 6.4 MB | xh bf16 9.6 MB | Wfrag 49 KB
    char* ws = (char*)d_ws;
    int* cursor = (int*)ws;
    u16* bucket = (u16*)(ws + 200192);
    u16* xh     = (u16*)(ws + 200192 + 6400000);
    u16* Wfrag  = (u16*)(ws + 200192 + 6400000 + 9600000);

    hipMemsetAsync(cursor, 0, N_NODES * sizeof(int), stream);

    {
        dim3 grid(FILL_BLOCKS + CONV_BLOCKS + WCONV_BLOCKS);   // 4404
        sage_fill_conv<<<grid, 256, 0, stream>>>(src, dst, x, Wl, Wr,
                                                 cursor, bucket, xh, Wfrag);
    }
    {
        dim3 grid(AG_BLOCKS);                                  // 782
        sage_agg_gemm<<<grid, 256, 0, stream>>>(xh, cursor, bucket, Wfrag, bl, out);
    }
}